// Round 8
// baseline (85.348 us; speedup 1.0000x reference)
//
#include <hip/hip_runtime.h>
#include <hip/hip_fp8.h>

#define N 8192
#define D 200
#define NSTEP 7            // 7 * 32 = 224 K fed to MFMA (200 real + fp8-zero pad)
#define TB 128             // tile edge, ONE TILE PER BLOCK (4 waves, 64x64 quadrant each)
#define NT 64              // tile grid dim = N/TB
#define TPP 65             // tiles per row-pair: row q has 64-q, row 63-q has q+1
#define NBLK (32 * TPP)    // 2080 triangle tiles == blocks (2080 % 8 == 0)
#define FSTEP 512          // bytes per fragment-step block (64 lanes x 8B)
#define PSTRIDE (NSTEP * FSTEP)        // 3584 B per 16-row panel
#define PANEL_T (8 * PSTRIDE)          // 28672 B per 128-row tile (contiguous!)
#define NPANEL (N / 16)                // 512 panels
#define XBSZ ((size_t)NPANEL * PSTRIDE)  // 1.84 MB, L2-resident
#define NCELL 256

typedef float f32x4 __attribute__((ext_vector_type(4)));
#define AS3 __attribute__((address_space(3)))
#define AS1 __attribute__((address_space(1)))

// ---- prep: cast to fp8 e4m3, store in MFMA-fragment-native order ----
// (verified layout, rounds 3/4: byte k of row r ->
//   (r/16)*3584 + (k/32)*512 + ((k%32)/8)*128 + (r%16)*8 + (k%8))
// Block 0 also zeroes the 256 reduction cells.
__global__ __launch_bounds__(256) void prep_kernel(
    const float* __restrict__ x, const int* __restrict__ labels,
    unsigned char* __restrict__ xb, float* __restrict__ sq,
    int* __restrict__ lab, double* __restrict__ cells) {
  if (blockIdx.x == 0) cells[threadIdx.x] = 0.0;   // NCELL == blockDim
  int row = blockIdx.x * 4 + (threadIdx.x >> 6);   // one wave per row
  int lane = threadIdx.x & 63;
  const float* xr = x + (size_t)row * D;
  int k0 = lane * 4;
  float4 f = {0.f, 0.f, 0.f, 0.f};
  if (k0 < D) f = *(const float4*)(xr + k0);       // lane<50 fully in-bounds
  float s = 0.f;
  unsigned char q[4];
  float ff[4] = {f.x, f.y, f.z, f.w};
#pragma unroll
  for (int c = 0; c < 4; ++c) {
    float v = (k0 + c < D) ? ff[c] : 0.f;
    __hip_fp8_e4m3 h(v);                           // OCP e4m3 RNE
    q[c] = h.__x;
    float fb = (float)h;
    s += fb * fb;                                  // norm of the fp8-rounded row
  }
  if (k0 < NSTEP * 32) {                           // lanes 0..55 (50..55 write zeros)
    unsigned char* dst = xb + (size_t)(row >> 4) * PSTRIDE
                       + (k0 >> 5) * FSTEP          // step
                       + ((k0 & 31) >> 3) * 128     // quad chunk
                       + (row & 15) * 8             // row within panel
                       + (k0 & 7);                  // 0 or 4
    *(uchar4*)dst = *(uchar4*)q;
  }
#pragma unroll
  for (int m = 32; m; m >>= 1) s += __shfl_xor(s, m);
  if (lane == 0) {
    sq[row] = s;
    lab[row] = labels[row];
  }
}

// ---- gram: one 128x128 tile per block. Fragment-native LDS: staging is two
// ---- contiguous 28.7 KB copies, every ds_read is base+imm+lane*8 (512 B
// ---- contiguous -> ZERO bank conflicts, zero address VALU). Anti-lockstep:
// ---- the second resident cohort sleeps ~2560 cy once, so co-resident
// ---- blocks stay phase-shifted (stage overlaps CU-mate's compute) for the
// ---- whole kernel. 57.3 KB LDS -> 2 blocks/CU.
__global__ __launch_bounds__(256, 2) void gram_kernel(
    const unsigned char* __restrict__ xb, const float* __restrict__ sq,
    const int* __restrict__ lab, double* __restrict__ cells) {
  __shared__ __align__(16) unsigned char sA[PANEL_T];
  __shared__ __align__(16) unsigned char sB[PANEL_T];

  if ((blockIdx.x >> 8) & 1)                       // second cohort: one-time stagger
    __builtin_amdgcn_s_sleep(40);                  // ~2560 cycles

  const int t = threadIdx.x;
  const int b = (blockIdx.x & 7) * (NBLK / 8) + (blockIdx.x >> 3);  // XCD swizzle
  const int q = b / TPP, idx = b - q * TPP;        // row-pair decode
  const int n1 = NT - q;
  const int I = (idx < n1) ? q : NT - 1 - q;
  const int J = (idx < n1) ? q + idx : (NT - 1 - q) + (idx - n1);

  auto stage = [&](const unsigned char* g, unsigned char* sh) {
#pragma unroll
    for (int c = 0; c < 7; ++c) {                  // 7 * 4096 = 28672 exactly
      int off = c * 4096 + t * 16;
      __builtin_amdgcn_global_load_lds((const AS1 void*)(g + off),
                                       (AS3 void*)(sh + off), 16, 0, 0);
    }
  };
  stage(xb + (size_t)(8 * I) * PSTRIDE, sA);
  stage(xb + (size_t)(8 * J) * PSTRIDE, sB);

  // ---- hoisted epilogue operands (ride the same vmcnt drain as staging) ----
  const int wid = t >> 6, lane = t & 63;
  const int col = lane & 15, quad = lane >> 4;
  const int waveM = (wid >> 1) * 64, waveN = (wid & 1) * 64;
  const int i0 = I * TB + waveM, j0 = J * TB + waveN;
  int labj[4];
  float sqj[4];
#pragma unroll
  for (int ni = 0; ni < 4; ++ni) {
    int j = j0 + ni * 16 + col;
    labj[ni] = lab[j];
    sqj[ni] = sq[j];
  }
  float4 sqi4[4];
  int4 li4[4];
#pragma unroll
  for (int mi = 0; mi < 4; ++mi) {
    sqi4[mi] = *(const float4*)(sq + i0 + mi * 16 + quad * 4);
    li4[mi] = *(const int4*)(lab + i0 + mi * 16 + quad * 4);
  }
  __syncthreads();                                 // drains staging vmcnt + barrier

  // ---- K-loop from LDS: conflict-free ds_read_b64, compile-time offsets ----
  const int pA = (waveM >> 4) * PSTRIDE + lane * 8;   // wave's A panel base
  const int pB = (waveN >> 4) * PSTRIDE + lane * 8;   // wave's B panel base
  f32x4 acc[4][4] = {};
  __builtin_amdgcn_s_setprio(1);
#pragma unroll
  for (int step = 0; step < NSTEP; ++step) {
    long a[4], bf[4];
#pragma unroll
    for (int mi = 0; mi < 4; ++mi)
      a[mi] = *(const long*)(sA + pA + mi * PSTRIDE + step * FSTEP);
#pragma unroll
    for (int ni = 0; ni < 4; ++ni)
      bf[ni] = *(const long*)(sB + pB + ni * PSTRIDE + step * FSTEP);
#pragma unroll
    for (int mi = 0; mi < 4; ++mi)
#pragma unroll
      for (int ni = 0; ni < 4; ++ni)
        acc[mi][ni] = __builtin_amdgcn_mfma_f32_16x16x32_fp8_fp8(
            a[mi], bf[ni], acc[mi][ni], 0, 0, 0);
  }
  __builtin_amdgcn_s_setprio(0);

  // ---- epilogue: D[m = quad*4 + r][n = col] (verified layout) ----
  float rs = 0.f, tot;
  if (I != J) {
#pragma unroll
    for (int mi = 0; mi < 4; ++mi) {
      float sqi[4] = {sqi4[mi].x, sqi4[mi].y, sqi4[mi].z, sqi4[mi].w};
      int li[4] = {li4[mi].x, li4[mi].y, li4[mi].z, li4[mi].w};
#pragma unroll
      for (int r = 0; r < 4; ++r)
#pragma unroll
        for (int ni = 0; ni < 4; ++ni) {
          float g = acc[mi][ni][r];
          float d2 = fmaxf(fmaf(-2.f, g, sqi[r] + sqj[ni]), 0.f);
          float dist = __builtin_amdgcn_sqrtf(d2);
          rs += (li[r] == labj[ni]) ? dist : -dist;
        }
    }
    tot = 2.f * rs;                                // mirror tile not launched
  } else {
#pragma unroll
    for (int mi = 0; mi < 4; ++mi) {
      float sqi[4] = {sqi4[mi].x, sqi4[mi].y, sqi4[mi].z, sqi4[mi].w};
      int li[4] = {li4[mi].x, li4[mi].y, li4[mi].z, li4[mi].w};
#pragma unroll
      for (int r = 0; r < 4; ++r) {
        int i = i0 + mi * 16 + quad * 4 + r;
#pragma unroll
        for (int ni = 0; ni < 4; ++ni) {
          int j = j0 + ni * 16 + col;
          float g = acc[mi][ni][r];
          float d2 = fmaxf(fmaf(-2.f, g, sqi[r] + sqj[ni]), 0.f);
          float dist = __builtin_amdgcn_sqrtf(d2);
          float c = (li[r] == labj[ni]) ? dist : -dist;
          rs += (i == j) ? 0.f : c;
        }
      }
    }
    tot = rs;
  }

  // ---- per-wave f64 scatter atomic (256 cells: no contention) ----
#pragma unroll
  for (int m = 32; m; m >>= 1) tot += __shfl_xor(tot, m);
  if (lane == 0)
    atomicAdd(&cells[(b * 4 + wid) & (NCELL - 1)], (double)tot);
}

// ---------------- final mean (256 doubles only) ----------------
__global__ __launch_bounds__(256) void reduce_kernel(
    const double* __restrict__ cells, float* __restrict__ out) {
  __shared__ double wsum[4];
  double s = cells[threadIdx.x];
#pragma unroll
  for (int m = 32; m; m >>= 1) s += __shfl_xor(s, m);
  if ((threadIdx.x & 63) == 0) wsum[threadIdx.x >> 6] = s;
  __syncthreads();
  if (threadIdx.x == 0)
    out[0] = (float)((wsum[0] + wsum[1] + wsum[2] + wsum[3]) / (double)N);
}

extern "C" void kernel_launch(void* const* d_in, const int* in_sizes, int n_in,
                              void* d_out, int out_size, void* d_ws, size_t ws_size,
                              hipStream_t stream) {
  const float* x = (const float*)d_in[0];
  const int* labels = (const int*)d_in[1];
  char* ws = (char*)d_ws;
  unsigned char* xb = (unsigned char*)ws;                      // XBSZ = 1.84 MB
  float* sq = (float*)(ws + XBSZ);                             // N*4
  int* lab = (int*)(ws + XBSZ + (size_t)N * 4);                // N*4
  double* cells = (double*)(ws + XBSZ + (size_t)N * 8);        // 256*8
  float* out = (float*)d_out;

  prep_kernel<<<N / 4, 256, 0, stream>>>(x, labels, xb, sq, lab, cells);
  gram_kernel<<<NBLK, 256, 0, stream>>>(xb, sq, lab, cells);
  reduce_kernel<<<1, 256, 0, stream>>>(cells, out);
}